// Round 6
// baseline (1332.644 us; speedup 1.0000x reference)
//
#include <hip/hip_runtime.h>
#include <hip/hip_bf16.h>

#define Bb 4
#define Tt 256
#define Uu 128
#define H1 512
#define H2 640
#define Dd 640
#define V1c 1025

typedef __bf16 bf16x8 __attribute__((ext_vector_type(8)));
typedef unsigned short ushort8 __attribute__((ext_vector_type(8)));
typedef unsigned short ushort4v __attribute__((ext_vector_type(4)));
typedef float floatx4 __attribute__((ext_vector_type(4)));

static __device__ __forceinline__ unsigned short f2bf(float x) {
    union { float f; unsigned u; } a; a.f = x;
    unsigned r = a.u + 0x7fffu + ((a.u >> 16) & 1u);
    return (unsigned short)(r >> 16);
}
static __device__ __forceinline__ float bf2f(unsigned short x) {
    union { unsigned u; float f; } a; a.u = ((unsigned)x) << 16; return a.f;
}

// ---------------- f and g linear layers, fused in one launch ----------------
__global__ __launch_bounds__(640) void fg_fused(const float* __restrict__ enc,
                                                const float* __restrict__ Wenc,
                                                const float* __restrict__ benc,
                                                float* __restrict__ f,
                                                const float* __restrict__ pred,
                                                const float* __restrict__ Wpred,
                                                const float* __restrict__ bpred,
                                                float* __restrict__ g) {
    __shared__ float s[640 * 8];
    const bool isF = blockIdx.x < 128;
    const float* in   = isF ? enc : pred;
    const float* W    = isF ? Wenc : Wpred;
    const float* bias = isF ? benc : bpred;
    float* out        = isF ? f : g;
    const int H    = isF ? H1 : H2;
    const int Tdim = isF ? Tt : Uu;
    const int blk  = isF ? (int)blockIdx.x : (int)blockIdx.x - 128;
    const int tBlocks = Tdim >> 3;
    const int b  = blk / tBlocks;
    const int t0 = (blk % tBlocks) << 3;
    const float* inB = in + (size_t)b * H * Tdim + t0;
    const int tid = threadIdx.x;

    for (int h = tid; h < H; h += 640) {
        float4 v0 = *(const float4*)(inB + (size_t)h * Tdim);
        float4 v1 = *(const float4*)(inB + (size_t)h * Tdim + 4);
        *(float4*)(&s[h * 8])     = v0;
        *(float4*)(&s[h * 8 + 4]) = v1;
    }
    __syncthreads();

    const int d = tid;
    float acc[8];
    #pragma unroll
    for (int j = 0; j < 8; ++j) acc[j] = 0.f;
    #pragma unroll 4
    for (int h = 0; h < H; ++h) {
        float w = W[(size_t)h * Dd + d];
        float4 s0 = *(const float4*)(&s[h * 8]);
        float4 s1 = *(const float4*)(&s[h * 8 + 4]);
        acc[0] += s0.x * w; acc[1] += s0.y * w; acc[2] += s0.z * w; acc[3] += s0.w * w;
        acc[4] += s1.x * w; acc[5] += s1.y * w; acc[6] += s1.z * w; acc[7] += s1.w * w;
    }
    float bv = bias[d];
    float* o = out + ((size_t)b * Tdim + t0) * Dd + d;
    #pragma unroll
    for (int j = 0; j < 8; ++j) o[(size_t)j * Dd] = acc[j] + bv;
}

// Wb[v][d] = bf16(W_out[d][v]) for v<1024 ; wtail[d] = W_out[d][1024]
__global__ __launch_bounds__(256) void conv_wout(const float* __restrict__ Wout,
                                                 unsigned short* __restrict__ Wb,
                                                 float* __restrict__ wtail) {
    __shared__ float tile[32][33];
    int tx = threadIdx.x & 31, ty = threadIdx.x >> 5;
    int vb = (blockIdx.x & 31) * 32;
    int db = (blockIdx.x >> 5) * 32;
    #pragma unroll
    for (int j = 0; j < 4; ++j) {
        int dd = db + ty + 8 * j;
        tile[ty + 8 * j][tx] = Wout[(size_t)dd * V1c + vb + tx];
    }
    __syncthreads();
    #pragma unroll
    for (int j = 0; j < 4; ++j) {
        int v = vb + ty + 8 * j;
        Wb[(size_t)v * Dd + db + tx] = f2bf(tile[tx][ty + 8 * j]);
    }
    if (blockIdx.x == 0) {
        for (int dd = threadIdx.x; dd < 640; dd += 256) wtail[dd] = Wout[(size_t)dd * V1c + 1024];
    }
}

// ---------------- fused joint + log-softmax ----------------
// 2048 blocks x 1024 thr (16 waves). Block: 64 rows x 1025 cols.
// Wave grid: 4 row-groups x 4 col-groups; wave tile 16 x 256 -> acc[16] = 64 regs.
// Unified VGPR+AGPR cap at 1024 thr is 128/thread -> 16 waves/CU (~50% occ).
// cg = w&3 so each SIMD's 4 waves read identical Wb lines (4x L1 reuse).
__global__ __launch_bounds__(1024) void joint_main(const float* __restrict__ f,
                                                   const float* __restrict__ g,
                                                   const unsigned short* __restrict__ Wb,
                                                   const float* __restrict__ wtail,
                                                   const float* __restrict__ b_out,
                                                   float* __restrict__ out) {
    __shared__ __align__(16) union UU {
        struct { unsigned short hlds[64 * 328]; float wtld[640]; } a;  // 44544 B
        float sOut[16 * 1025];                                         // 65600 B
    } u;
    __shared__ float sPart[4 * 64];
    __shared__ float sRed[64];
    __shared__ float sTail[64];

    const int tid = threadIdx.x;
    const int l = tid & 63;
    const int w = tid >> 6;       // wave 0..15
    const int cg = w & 3;         // column group (same per SIMD)
    const int rh = w >> 2;        // row group 0..3
    const int l15 = l & 15;
    const int lg = l >> 4;

    const int blk = blockIdx.x;
    const int uhalf = blk & 1;
    const int t = (blk >> 1) & 255;
    const int b = blk >> 9;
    const int u0 = uhalf * 64;
    const size_t fbase = ((size_t)b * Tt + t) * Dd;
    const size_t gbase = ((size_t)b * Uu + u0) * Dd;
    const size_t rowbase = (size_t)(b * Tt + t) * Uu + u0;

    for (int i = tid; i < Dd; i += 1024) u.a.wtld[i] = wtail[i];

    floatx4 acc[16];
    #pragma unroll
    for (int j = 0; j < 16; ++j) acc[j] = (floatx4){0.f, 0.f, 0.f, 0.f};

    // B pointer: this wave's columns cg*256 + nt*16 + l15 ; k offset lg*8
    const unsigned short* __restrict__ bptr = Wb + (size_t)(cg * 256 + l15) * Dd + lg * 8;
    float tailAcc = 0.f;
    const int srow = tid >> 4;    // 64 rows, 16 threads each
    const int ssub = tid & 15;

    for (int half = 0; half < 2; ++half) {
        const int dhb = half * 320;
        __syncthreads();
        // ---- stage h = relu(f+g): 64 rows x 320 cols bf16; 16 threads/row ----
        {
            const int row = tid >> 4;
            #pragma unroll
            for (int j = 0; j < 5; ++j) {
                int c4 = (tid & 15) + 16 * j;       // float4 slot 0..79
                int d = dhb + c4 * 4;
                float4 fv = *(const float4*)(f + fbase + d);
                float4 gv = *(const float4*)(g + gbase + (size_t)row * Dd + d);
                float h0 = fv.x + gv.x; h0 = h0 > 0.f ? h0 : 0.f;
                float h1 = fv.y + gv.y; h1 = h1 > 0.f ? h1 : 0.f;
                float h2 = fv.z + gv.z; h2 = h2 > 0.f ? h2 : 0.f;
                float h3 = fv.w + gv.w; h3 = h3 > 0.f ? h3 : 0.f;
                ushort4v pk;
                pk.x = f2bf(h0); pk.y = f2bf(h1); pk.z = f2bf(h2); pk.w = f2bf(h3);
                *(ushort4v*)(&u.a.hlds[row * 328 + c4 * 4]) = pk;
            }
        }
        __syncthreads();

        // ---- K loop: 10 steps of 32 ----
        #pragma unroll 2
        for (int ks = 0; ks < 10; ++ks) {
            ushort8 av = *(const ushort8*)(&u.a.hlds[(rh * 16 + l15) * 328 + ks * 32 + lg * 8]);
            bf16x8 afrag = __builtin_bit_cast(bf16x8, av);
            #pragma unroll
            for (int nt = 0; nt < 16; ++nt) {
                ushort8 bv = *(const ushort8*)(bptr + (size_t)nt * 16 * Dd + dhb + ks * 32);
                bf16x8 bfrag = __builtin_bit_cast(bf16x8, bv);
                acc[nt] = __builtin_amdgcn_mfma_f32_16x16x32_bf16(afrag, bfrag, acc[nt], 0, 0, 0);
            }
        }

        // ---- tail column partial: dot(h_row, wtail) from LDS ----
        #pragma unroll
        for (int j = 0; j < 5; ++j) {
            int c4 = ssub + 16 * j;
            ushort4v hv = *(const ushort4v*)(&u.a.hlds[srow * 328 + c4 * 4]);
            float4 wv = *(const float4*)(&u.a.wtld[dhb + c4 * 4]);
            tailAcc += bf2f(hv.x) * wv.x + bf2f(hv.y) * wv.y +
                       bf2f(hv.z) * wv.z + bf2f(hv.w) * wv.w;
        }
    }

    tailAcc += __shfl_xor(tailAcc, 1);
    tailAcc += __shfl_xor(tailAcc, 2);
    tailAcc += __shfl_xor(tailAcc, 4);
    tailAcc += __shfl_xor(tailAcc, 8);
    if (ssub == 0) sTail[srow] = tailAcc + b_out[1024];

    // ---- + b_out ----
    #pragma unroll
    for (int nt = 0; nt < 16; ++nt) {
        float bo = b_out[cg * 256 + nt * 16 + l15];
        #pragma unroll
        for (int r = 0; r < 4; ++r) acc[nt][r] += bo;
    }

    // ---- row max (over this wave's 256 cols, then combine 4 cgs) ----
    #pragma unroll
    for (int r = 0; r < 4; ++r) {
        float m = acc[0][r];
        #pragma unroll
        for (int nt = 1; nt < 16; ++nt) m = fmaxf(m, acc[nt][r]);
        #pragma unroll
        for (int msk = 1; msk < 16; msk <<= 1) m = fmaxf(m, __shfl_xor(m, msk));
        if (l15 == 0) sPart[cg * 64 + rh * 16 + lg * 4 + r] = m;
    }
    __syncthreads();
    if (tid < 64) {
        float m = sTail[tid];
        #pragma unroll
        for (int c = 0; c < 4; ++c) m = fmaxf(m, sPart[c * 64 + tid]);
        sRed[tid] = m;
    }
    __syncthreads();

    // ---- sum exp ----
    #pragma unroll
    for (int r = 0; r < 4; ++r) {
        int row = rh * 16 + lg * 4 + r;
        float mx = sRed[row];
        float sv = 0.f;
        #pragma unroll
        for (int nt = 0; nt < 16; ++nt) sv += __expf(acc[nt][r] - mx);
        #pragma unroll
        for (int msk = 1; msk < 16; msk <<= 1) sv += __shfl_xor(sv, msk);
        if (l15 == 0) sPart[cg * 64 + row] = sv;
    }
    __syncthreads();
    if (tid < 64) {
        float mx = sRed[tid];
        float sv = __expf(sTail[tid] - mx);
        #pragma unroll
        for (int c = 0; c < 4; ++c) sv += sPart[c * 64 + tid];
        sRed[tid] = mx + logf(sv);  // lse
    }
    __syncthreads();   // sRed ready; hlds/wtld dead -> sOut aliasing OK

    // ---- write: 4 groups of 16 rows (one rh each), via LDS, float4 NT drain ----
    for (int grp = 0; grp < 4; ++grp) {
        if (rh == grp) {
            #pragma unroll
            for (int nt = 0; nt < 16; ++nt) {
                #pragma unroll
                for (int r = 0; r < 4; ++r) {
                    u.sOut[(lg * 4 + r) * 1025 + cg * 256 + nt * 16 + l15] =
                        acc[nt][r] - sRed[grp * 16 + lg * 4 + r];
                }
            }
        }
        if (tid < 16) u.sOut[tid * 1025 + 1024] = sTail[grp * 16 + tid] - sRed[grp * 16 + tid];
        __syncthreads();
        // 16*1025 = 16400 floats = 4100 float4, base 16B-aligned
        float* outp = out + (rowbase + grp * 16) * (size_t)V1c;
        #pragma unroll
        for (int k = 0; k < 4; ++k) {
            int i4 = tid + 1024 * k;
            floatx4 v = *(const floatx4*)(&u.sOut[4 * i4]);
            __builtin_nontemporal_store(v, (floatx4*)(outp + 4 * i4));
        }
        if (tid < 4) {
            int i4 = tid + 4096;
            floatx4 v = *(const floatx4*)(&u.sOut[4 * i4]);
            __builtin_nontemporal_store(v, (floatx4*)(outp + 4 * i4));
        }
        __syncthreads();
    }
}

extern "C" void kernel_launch(void* const* d_in, const int* in_sizes, int n_in,
                              void* d_out, int out_size, void* d_ws, size_t ws_size,
                              hipStream_t stream) {
    const float* enc   = (const float*)d_in[0];
    const float* pred  = (const float*)d_in[1];
    const float* Wenc  = (const float*)d_in[2];
    const float* benc  = (const float*)d_in[3];
    const float* Wpred = (const float*)d_in[4];
    const float* bpred = (const float*)d_in[5];
    const float* Wout  = (const float*)d_in[6];
    const float* bout  = (const float*)d_in[7];

    float* f = (float*)d_ws;
    float* g = f + (size_t)Bb * Tt * Dd;
    unsigned short* Wb = (unsigned short*)(g + (size_t)Bb * Uu * Dd);
    float* wtail = (float*)(Wb + 1024 * Dd);

    fg_fused<<<192, 640, 0, stream>>>(enc, Wenc, benc, f, pred, Wpred, bpred, g);
    conv_wout<<<640, 256, 0, stream>>>(Wout, Wb, wtail);
    joint_main<<<Bb * Tt * 2, 1024, 0, stream>>>(f, g, Wb, wtail, bout, (float*)d_out);
}

// Round 7
// 662.096 us; speedup vs baseline: 2.0128x; 2.0128x over previous
//
#include <hip/hip_runtime.h>
#include <hip/hip_bf16.h>

#define Bb 4
#define Tt 256
#define Uu 128
#define H1 512
#define H2 640
#define Dd 640
#define V1c 1025

typedef __bf16 bf16x8 __attribute__((ext_vector_type(8)));
typedef unsigned short ushort8 __attribute__((ext_vector_type(8)));
typedef unsigned short ushort4v __attribute__((ext_vector_type(4)));
typedef float floatx4 __attribute__((ext_vector_type(4)));

static __device__ __forceinline__ unsigned short f2bf(float x) {
    union { float f; unsigned u; } a; a.f = x;
    unsigned r = a.u + 0x7fffu + ((a.u >> 16) & 1u);
    return (unsigned short)(r >> 16);
}
static __device__ __forceinline__ float bf2f(unsigned short x) {
    union { unsigned u; float f; } a; a.u = ((unsigned)x) << 16; return a.f;
}

// ---------------- f and g linear layers, fused in one launch ----------------
__global__ __launch_bounds__(640) void fg_fused(const float* __restrict__ enc,
                                                const float* __restrict__ Wenc,
                                                const float* __restrict__ benc,
                                                float* __restrict__ f,
                                                const float* __restrict__ pred,
                                                const float* __restrict__ Wpred,
                                                const float* __restrict__ bpred,
                                                float* __restrict__ g) {
    __shared__ float s[640 * 8];
    const bool isF = blockIdx.x < 128;
    const float* in   = isF ? enc : pred;
    const float* W    = isF ? Wenc : Wpred;
    const float* bias = isF ? benc : bpred;
    float* out        = isF ? f : g;
    const int H    = isF ? H1 : H2;
    const int Tdim = isF ? Tt : Uu;
    const int blk  = isF ? (int)blockIdx.x : (int)blockIdx.x - 128;
    const int tBlocks = Tdim >> 3;
    const int b  = blk / tBlocks;
    const int t0 = (blk % tBlocks) << 3;
    const float* inB = in + (size_t)b * H * Tdim + t0;
    const int tid = threadIdx.x;

    for (int h = tid; h < H; h += 640) {
        float4 v0 = *(const float4*)(inB + (size_t)h * Tdim);
        float4 v1 = *(const float4*)(inB + (size_t)h * Tdim + 4);
        *(float4*)(&s[h * 8])     = v0;
        *(float4*)(&s[h * 8 + 4]) = v1;
    }
    __syncthreads();

    const int d = tid;
    float acc[8];
    #pragma unroll
    for (int j = 0; j < 8; ++j) acc[j] = 0.f;
    #pragma unroll 4
    for (int h = 0; h < H; ++h) {
        float w = W[(size_t)h * Dd + d];
        float4 s0 = *(const float4*)(&s[h * 8]);
        float4 s1 = *(const float4*)(&s[h * 8 + 4]);
        acc[0] += s0.x * w; acc[1] += s0.y * w; acc[2] += s0.z * w; acc[3] += s0.w * w;
        acc[4] += s1.x * w; acc[5] += s1.y * w; acc[6] += s1.z * w; acc[7] += s1.w * w;
    }
    float bv = bias[d];
    float* o = out + ((size_t)b * Tdim + t0) * Dd + d;
    #pragma unroll
    for (int j = 0; j < 8; ++j) o[(size_t)j * Dd] = acc[j] + bv;
}

// Wb[v][d] = bf16(W_out[d][v]) for v<1024 ; wtail[d] = W_out[d][1024]
__global__ __launch_bounds__(256) void conv_wout(const float* __restrict__ Wout,
                                                 unsigned short* __restrict__ Wb,
                                                 float* __restrict__ wtail) {
    __shared__ float tile[32][33];
    int tx = threadIdx.x & 31, ty = threadIdx.x >> 5;
    int vb = (blockIdx.x & 31) * 32;
    int db = (blockIdx.x >> 5) * 32;
    #pragma unroll
    for (int j = 0; j < 4; ++j) {
        int dd = db + ty + 8 * j;
        tile[ty + 8 * j][tx] = Wout[(size_t)dd * V1c + vb + tx];
    }
    __syncthreads();
    #pragma unroll
    for (int j = 0; j < 4; ++j) {
        int v = vb + ty + 8 * j;
        Wb[(size_t)v * Dd + db + tx] = f2bf(tile[tx][ty + 8 * j]);
    }
    if (blockIdx.x == 0) {
        for (int dd = threadIdx.x; dd < 640; dd += 256) wtail[dd] = Wout[(size_t)dd * V1c + 1024];
    }
}

// ---------------- fused joint + log-softmax ----------------
// 2048 blocks x 512 thr (8 waves). Block: 64 rows x 1025 cols; wave tile 64x128
// (B-reuse 4 MFMAs per B-load -- R6 showed reducing this ratio is L2-BW fatal).
// Epilogue: direct PLAIN dword stores from acc (no NT, no LDS restage):
// stores complete at L2 speed, HBM writeback overlaps next block's compute.
__global__ __launch_bounds__(512, 2) void joint_main(const float* __restrict__ f,
                                                     const float* __restrict__ g,
                                                     const unsigned short* __restrict__ Wb,
                                                     const float* __restrict__ wtail,
                                                     const float* __restrict__ b_out,
                                                     float* __restrict__ out) {
    __shared__ __align__(16) struct {
        unsigned short hlds[64 * 328];
        float wtld[640];
    } u;
    __shared__ float sPart[8 * 64];
    __shared__ float sRed[64];
    __shared__ float sTail[64];

    const int tid = threadIdx.x;
    const int l = tid & 63;
    const int w = tid >> 6;
    const int l15 = l & 15;
    const int lg = l >> 4;

    const int blk = blockIdx.x;
    const int uhalf = blk & 1;
    const int t = (blk >> 1) & 255;
    const int b = blk >> 9;
    const int u0 = uhalf * 64;
    const size_t fbase = ((size_t)b * Tt + t) * Dd;
    const size_t gbase = ((size_t)b * Uu + u0) * Dd;
    const size_t rowbase = (size_t)(b * Tt + t) * Uu + u0;

    // stage wtail (fp32) into LDS
    for (int i = tid; i < Dd; i += 512) u.wtld[i] = wtail[i];

    floatx4 acc[4][8];
    #pragma unroll
    for (int i = 0; i < 4; ++i)
        #pragma unroll
        for (int j = 0; j < 8; ++j) acc[i][j] = (floatx4){0.f, 0.f, 0.f, 0.f};

    const unsigned short* __restrict__ bptr = Wb + (size_t)(w * 128 + l15) * Dd + lg * 8;
    float tailAcc = 0.f;
    const int srow = w * 8 + (l >> 3);
    const int ssub = l & 7;

    for (int half = 0; half < 2; ++half) {
        const int dhb = half * 320;
        __syncthreads();
        // ---- stage h = relu(f+g) panel: 64 rows x 320 cols bf16 ----
        {
            const int row = tid >> 3;
            #pragma unroll
            for (int j = 0; j < 10; ++j) {
                int c4 = (tid & 7) + 8 * j;
                int d = dhb + c4 * 4;
                float4 fv = *(const float4*)(f + fbase + d);
                float4 gv = *(const float4*)(g + gbase + (size_t)row * Dd + d);
                float h0 = fv.x + gv.x; h0 = h0 > 0.f ? h0 : 0.f;
                float h1 = fv.y + gv.y; h1 = h1 > 0.f ? h1 : 0.f;
                float h2 = fv.z + gv.z; h2 = h2 > 0.f ? h2 : 0.f;
                float h3 = fv.w + gv.w; h3 = h3 > 0.f ? h3 : 0.f;
                ushort4v pk;
                pk.x = f2bf(h0); pk.y = f2bf(h1); pk.z = f2bf(h2); pk.w = f2bf(h3);
                *(ushort4v*)(&u.hlds[row * 328 + c4 * 4]) = pk;
            }
        }
        __syncthreads();

        // ---- K loop: 10 steps of 32, B double-buffered in regs ----
        ushort8 Bbuf[2][8];
        #pragma unroll
        for (int nt = 0; nt < 8; ++nt)
            Bbuf[0][nt] = *(const ushort8*)(bptr + (size_t)nt * 16 * Dd + dhb);
        #pragma unroll
        for (int ks = 0; ks < 10; ++ks) {
            if (ks < 9) {
                #pragma unroll
                for (int nt = 0; nt < 8; ++nt)
                    Bbuf[(ks + 1) & 1][nt] =
                        *(const ushort8*)(bptr + (size_t)nt * 16 * Dd + dhb + (ks + 1) * 32);
            }
            bf16x8 afrag[4];
            #pragma unroll
            for (int mt = 0; mt < 4; ++mt) {
                ushort8 av = *(const ushort8*)(&u.hlds[(mt * 16 + l15) * 328 + ks * 32 + lg * 8]);
                afrag[mt] = __builtin_bit_cast(bf16x8, av);
            }
            #pragma unroll
            for (int nt = 0; nt < 8; ++nt) {
                bf16x8 bfrag = __builtin_bit_cast(bf16x8, Bbuf[ks & 1][nt]);
                #pragma unroll
                for (int mt = 0; mt < 4; ++mt) {
                    acc[mt][nt] = __builtin_amdgcn_mfma_f32_16x16x32_bf16(
                        afrag[mt], bfrag, acc[mt][nt], 0, 0, 0);
                }
            }
        }

        // ---- tail column partial: dot(h_row, wtail) from LDS ----
        #pragma unroll
        for (int j = 0; j < 10; ++j) {
            int c4 = ssub + 8 * j;
            ushort4v hv = *(const ushort4v*)(&u.hlds[srow * 328 + c4 * 4]);
            float4 wv = *(const float4*)(&u.wtld[dhb + c4 * 4]);
            tailAcc += bf2f(hv.x) * wv.x + bf2f(hv.y) * wv.y +
                       bf2f(hv.z) * wv.z + bf2f(hv.w) * wv.w;
        }
    }

    tailAcc += __shfl_xor(tailAcc, 1);
    tailAcc += __shfl_xor(tailAcc, 2);
    tailAcc += __shfl_xor(tailAcc, 4);
    if (ssub == 0) sTail[srow] = tailAcc + b_out[1024];

    // ---- + b_out ----
    #pragma unroll
    for (int nt = 0; nt < 8; ++nt) {
        float bo = b_out[w * 128 + nt * 16 + l15];
        #pragma unroll
        for (int mt = 0; mt < 4; ++mt)
            #pragma unroll
            for (int r = 0; r < 4; ++r) acc[mt][nt][r] += bo;
    }

    // ---- row max ----
    #pragma unroll
    for (int mt = 0; mt < 4; ++mt) {
        #pragma unroll
        for (int r = 0; r < 4; ++r) {
            float m = acc[mt][0][r];
            #pragma unroll
            for (int nt = 1; nt < 8; ++nt) m = fmaxf(m, acc[mt][nt][r]);
            #pragma unroll
            for (int msk = 1; msk < 16; msk <<= 1) m = fmaxf(m, __shfl_xor(m, msk));
            if (l15 == 0) sPart[w * 64 + mt * 16 + lg * 4 + r] = m;
        }
    }
    __syncthreads();
    if (tid < 64) {
        float m = sTail[tid];
        #pragma unroll
        for (int ww = 0; ww < 8; ++ww) m = fmaxf(m, sPart[ww * 64 + tid]);
        sRed[tid] = m;
    }
    __syncthreads();

    // ---- sum exp ----
    #pragma unroll
    for (int mt = 0; mt < 4; ++mt) {
        #pragma unroll
        for (int r = 0; r < 4; ++r) {
            int row = mt * 16 + lg * 4 + r;
            float mx = sRed[row];
            float sv = 0.f;
            #pragma unroll
            for (int nt = 0; nt < 8; ++nt) sv += __expf(acc[mt][nt][r] - mx);
            #pragma unroll
            for (int msk = 1; msk < 16; msk <<= 1) sv += __shfl_xor(sv, msk);
            if (l15 == 0) sPart[w * 64 + row] = sv;
        }
    }
    __syncthreads();
    if (tid < 64) {
        float mx = sRed[tid];
        float sv = __expf(sTail[tid] - mx);
        #pragma unroll
        for (int ww = 0; ww < 8; ++ww) sv += sPart[ww * 64 + tid];
        sRed[tid] = mx + logf(sv);  // lse
    }
    __syncthreads();

    // ---- write: direct plain stores from acc (L2 write-back, fire-and-forget).
    // Each wave instr: 4 rows x 64B full segments; block covers 64 full rows. ----
    #pragma unroll
    for (int mt = 0; mt < 4; ++mt) {
        float lse[4];
        #pragma unroll
        for (int r = 0; r < 4; ++r) lse[r] = sRed[mt * 16 + lg * 4 + r];
        #pragma unroll
        for (int nt = 0; nt < 8; ++nt) {
            #pragma unroll
            for (int r = 0; r < 4; ++r) {
                int row = mt * 16 + lg * 4 + r;
                int col = w * 128 + nt * 16 + l15;
                out[(rowbase + row) * (size_t)V1c + col] = acc[mt][nt][r] - lse[r];
            }
        }
    }
    if (tid < 64) {
        out[(rowbase + tid) * (size_t)V1c + 1024] = sTail[tid] - sRed[tid];
    }
}

extern "C" void kernel_launch(void* const* d_in, const int* in_sizes, int n_in,
                              void* d_out, int out_size, void* d_ws, size_t ws_size,
                              hipStream_t stream) {
    const float* enc   = (const float*)d_in[0];
    const float* pred  = (const float*)d_in[1];
    const float* Wenc  = (const float*)d_in[2];
    const float* benc  = (const float*)d_in[3];
    const float* Wpred = (const float*)d_in[4];
    const float* bpred = (const float*)d_in[5];
    const float* Wout  = (const float*)d_in[6];
    const float* bout  = (const float*)d_in[7];

    float* f = (float*)d_ws;
    float* g = f + (size_t)Bb * Tt * Dd;
    unsigned short* Wb = (unsigned short*)(g + (size_t)Bb * Uu * Dd);
    float* wtail = (float*)(Wb + 1024 * Dd);

    fg_fused<<<192, 640, 0, stream>>>(enc, Wenc, benc, f, pred, Wpred, bpred, g);
    conv_wout<<<640, 256, 0, stream>>>(Wout, Wb, wtail);
    joint_main<<<Bb * Tt * 2, 512, 0, stream>>>(f, g, Wb, wtail, bout, (float*)d_out);
}

// Round 8
// 645.079 us; speedup vs baseline: 2.0659x; 1.0264x over previous
//
#include <hip/hip_runtime.h>
#include <hip/hip_bf16.h>

#define Bb 4
#define Tt 256
#define Uu 128
#define H1 512
#define H2 640
#define Dd 640
#define V1c 1025

typedef __bf16 bf16x8 __attribute__((ext_vector_type(8)));
typedef unsigned short ushort8 __attribute__((ext_vector_type(8)));
typedef unsigned short ushort4v __attribute__((ext_vector_type(4)));
typedef float floatx4 __attribute__((ext_vector_type(4)));

static __device__ __forceinline__ unsigned short f2bf(float x) {
    union { float f; unsigned u; } a; a.f = x;
    unsigned r = a.u + 0x7fffu + ((a.u >> 16) & 1u);
    return (unsigned short)(r >> 16);
}
static __device__ __forceinline__ float bf2f(unsigned short x) {
    union { unsigned u; float f; } a; a.u = ((unsigned)x) << 16; return a.f;
}

// ---------------- f and g linear layers, fused in one launch ----------------
__global__ __launch_bounds__(640) void fg_fused(const float* __restrict__ enc,
                                                const float* __restrict__ Wenc,
                                                const float* __restrict__ benc,
                                                float* __restrict__ f,
                                                const float* __restrict__ pred,
                                                const float* __restrict__ Wpred,
                                                const float* __restrict__ bpred,
                                                float* __restrict__ g) {
    __shared__ float s[640 * 8];
    const bool isF = blockIdx.x < 128;
    const float* in   = isF ? enc : pred;
    const float* W    = isF ? Wenc : Wpred;
    const float* bias = isF ? benc : bpred;
    float* out        = isF ? f : g;
    const int H    = isF ? H1 : H2;
    const int Tdim = isF ? Tt : Uu;
    const int blk  = isF ? (int)blockIdx.x : (int)blockIdx.x - 128;
    const int tBlocks = Tdim >> 3;
    const int b  = blk / tBlocks;
    const int t0 = (blk % tBlocks) << 3;
    const float* inB = in + (size_t)b * H * Tdim + t0;
    const int tid = threadIdx.x;

    for (int h = tid; h < H; h += 640) {
        float4 v0 = *(const float4*)(inB + (size_t)h * Tdim);
        float4 v1 = *(const float4*)(inB + (size_t)h * Tdim + 4);
        *(float4*)(&s[h * 8])     = v0;
        *(float4*)(&s[h * 8 + 4]) = v1;
    }
    __syncthreads();

    const int d = tid;
    float acc[8];
    #pragma unroll
    for (int j = 0; j < 8; ++j) acc[j] = 0.f;
    #pragma unroll 4
    for (int h = 0; h < H; ++h) {
        float w = W[(size_t)h * Dd + d];
        float4 s0 = *(const float4*)(&s[h * 8]);
        float4 s1 = *(const float4*)(&s[h * 8 + 4]);
        acc[0] += s0.x * w; acc[1] += s0.y * w; acc[2] += s0.z * w; acc[3] += s0.w * w;
        acc[4] += s1.x * w; acc[5] += s1.y * w; acc[6] += s1.z * w; acc[7] += s1.w * w;
    }
    float bv = bias[d];
    float* o = out + ((size_t)b * Tdim + t0) * Dd + d;
    #pragma unroll
    for (int j = 0; j < 8; ++j) o[(size_t)j * Dd] = acc[j] + bv;
}

// Wb[v][d] = bf16(W_out[d][v]) for v<1024 ; wtail[d] = W_out[d][1024]
__global__ __launch_bounds__(256) void conv_wout(const float* __restrict__ Wout,
                                                 unsigned short* __restrict__ Wb,
                                                 float* __restrict__ wtail) {
    __shared__ float tile[32][33];
    int tx = threadIdx.x & 31, ty = threadIdx.x >> 5;
    int vb = (blockIdx.x & 31) * 32;
    int db = (blockIdx.x >> 5) * 32;
    #pragma unroll
    for (int j = 0; j < 4; ++j) {
        int dd = db + ty + 8 * j;
        tile[ty + 8 * j][tx] = Wout[(size_t)dd * V1c + vb + tx];
    }
    __syncthreads();
    #pragma unroll
    for (int j = 0; j < 4; ++j) {
        int v = vb + ty + 8 * j;
        Wb[(size_t)v * Dd + db + tx] = f2bf(tile[tx][ty + 8 * j]);
    }
    if (blockIdx.x == 0) {
        for (int dd = threadIdx.x; dd < 640; dd += 256) wtail[dd] = Wout[(size_t)dd * V1c + 1024];
    }
}

// ---------------- fused joint + log-softmax ----------------
// 2048 blocks x 1024 thr (16 waves, 4/SIMD for latency hiding). Block: 64 rows
// x 1025 cols. Wave tile 64 rows x 64 cols: acc[4][4]=64 regs (fits the 128-reg
// cap a 1024-thr block enforces; R6 proved no spill at this footprint) while
// KEEPING the 4:1 MFMA:B-load ratio (R6's 16x256 wave tile broke it -> 4x B
// traffic). B traffic unchanged vs R5 (1.31MB/block).
__global__ __launch_bounds__(1024) void joint_main(const float* __restrict__ f,
                                                   const float* __restrict__ g,
                                                   const unsigned short* __restrict__ Wb,
                                                   const float* __restrict__ wtail,
                                                   const float* __restrict__ b_out,
                                                   float* __restrict__ out) {
    __shared__ __align__(16) union UU {
        struct { unsigned short hlds[64 * 328]; float wtld[640]; } a;  // 44544 B
        float sOut[8 * 1025];                                          // 32800 B
    } u;
    __shared__ float sPart[16 * 64];
    __shared__ float sRed[64];
    __shared__ float sTail[64];

    const int tid = threadIdx.x;
    const int l = tid & 63;
    const int w = tid >> 6;       // wave 0..15 = column group (64 cols each)
    const int l15 = l & 15;
    const int lg = l >> 4;

    const int blk = blockIdx.x;
    const int uhalf = blk & 1;
    const int t = (blk >> 1) & 255;
    const int b = blk >> 9;
    const int u0 = uhalf * 64;
    const size_t fbase = ((size_t)b * Tt + t) * Dd;
    const size_t gbase = ((size_t)b * Uu + u0) * Dd;
    const size_t rowbase = (size_t)(b * Tt + t) * Uu + u0;

    // stage wtail (fp32) into LDS
    if (tid < Dd) u.a.wtld[tid] = wtail[tid];

    floatx4 acc[4][4];
    #pragma unroll
    for (int i = 0; i < 4; ++i)
        #pragma unroll
        for (int j = 0; j < 4; ++j) acc[i][j] = (floatx4){0.f, 0.f, 0.f, 0.f};

    const unsigned short* __restrict__ bptr = Wb + (size_t)(w * 64 + l15) * Dd + lg * 8;
    float tailAcc = 0.f;
    const int srow = tid >> 4;    // 64 rows, 16 threads each
    const int ssub = tid & 15;

    for (int half = 0; half < 2; ++half) {
        const int dhb = half * 320;
        __syncthreads();
        // ---- stage h = relu(f+g): 64 rows x 320 cols bf16; 16 threads/row ----
        {
            const int row = tid >> 4;
            #pragma unroll
            for (int j = 0; j < 5; ++j) {
                int c4 = (tid & 15) + 16 * j;       // float4 slot 0..79
                int d = dhb + c4 * 4;
                float4 fv = *(const float4*)(f + fbase + d);
                float4 gv = *(const float4*)(g + gbase + (size_t)row * Dd + d);
                float h0 = fv.x + gv.x; h0 = h0 > 0.f ? h0 : 0.f;
                float h1 = fv.y + gv.y; h1 = h1 > 0.f ? h1 : 0.f;
                float h2 = fv.z + gv.z; h2 = h2 > 0.f ? h2 : 0.f;
                float h3 = fv.w + gv.w; h3 = h3 > 0.f ? h3 : 0.f;
                ushort4v pk;
                pk.x = f2bf(h0); pk.y = f2bf(h1); pk.z = f2bf(h2); pk.w = f2bf(h3);
                *(ushort4v*)(&u.a.hlds[row * 328 + c4 * 4]) = pk;
            }
        }
        __syncthreads();

        // ---- K loop: 10 steps of 32, B double-buffered in regs ----
        ushort8 Bbuf[2][4];
        #pragma unroll
        for (int nt = 0; nt < 4; ++nt)
            Bbuf[0][nt] = *(const ushort8*)(bptr + (size_t)nt * 16 * Dd + dhb);
        #pragma unroll
        for (int ks = 0; ks < 10; ++ks) {
            if (ks < 9) {
                #pragma unroll
                for (int nt = 0; nt < 4; ++nt)
                    Bbuf[(ks + 1) & 1][nt] =
                        *(const ushort8*)(bptr + (size_t)nt * 16 * Dd + dhb + (ks + 1) * 32);
            }
            bf16x8 afrag[4];
            #pragma unroll
            for (int mt = 0; mt < 4; ++mt) {
                ushort8 av = *(const ushort8*)(&u.a.hlds[(mt * 16 + l15) * 328 + ks * 32 + lg * 8]);
                afrag[mt] = __builtin_bit_cast(bf16x8, av);
            }
            #pragma unroll
            for (int nt = 0; nt < 4; ++nt) {
                bf16x8 bfrag = __builtin_bit_cast(bf16x8, Bbuf[ks & 1][nt]);
                #pragma unroll
                for (int mt = 0; mt < 4; ++mt) {
                    acc[mt][nt] = __builtin_amdgcn_mfma_f32_16x16x32_bf16(
                        afrag[mt], bfrag, acc[mt][nt], 0, 0, 0);
                }
            }
        }

        // ---- tail column partial: dot(h_row, wtail) from LDS ----
        #pragma unroll
        for (int j = 0; j < 5; ++j) {
            int c4 = ssub + 16 * j;
            ushort4v hv = *(const ushort4v*)(&u.a.hlds[srow * 328 + c4 * 4]);
            float4 wv = *(const float4*)(&u.a.wtld[dhb + c4 * 4]);
            tailAcc += bf2f(hv.x) * wv.x + bf2f(hv.y) * wv.y +
                       bf2f(hv.z) * wv.z + bf2f(hv.w) * wv.w;
        }
    }

    tailAcc += __shfl_xor(tailAcc, 1);
    tailAcc += __shfl_xor(tailAcc, 2);
    tailAcc += __shfl_xor(tailAcc, 4);
    tailAcc += __shfl_xor(tailAcc, 8);
    if (ssub == 0) sTail[srow] = tailAcc + b_out[1024];

    // ---- + b_out ----
    #pragma unroll
    for (int nt = 0; nt < 4; ++nt) {
        float bo = b_out[w * 64 + nt * 16 + l15];
        #pragma unroll
        for (int mt = 0; mt < 4; ++mt)
            #pragma unroll
            for (int r = 0; r < 4; ++r) acc[mt][nt][r] += bo;
    }

    // ---- row max (per wave over its 64 cols, then combine 16 groups) ----
    #pragma unroll
    for (int mt = 0; mt < 4; ++mt) {
        #pragma unroll
        for (int r = 0; r < 4; ++r) {
            float m = acc[mt][0][r];
            #pragma unroll
            for (int nt = 1; nt < 4; ++nt) m = fmaxf(m, acc[mt][nt][r]);
            #pragma unroll
            for (int msk = 1; msk < 16; msk <<= 1) m = fmaxf(m, __shfl_xor(m, msk));
            if (l15 == 0) sPart[w * 64 + mt * 16 + lg * 4 + r] = m;
        }
    }
    __syncthreads();
    if (tid < 64) {
        float m = sTail[tid];
        #pragma unroll
        for (int ww = 0; ww < 16; ++ww) m = fmaxf(m, sPart[ww * 64 + tid]);
        sRed[tid] = m;
    }
    __syncthreads();

    // ---- sum exp ----
    #pragma unroll
    for (int mt = 0; mt < 4; ++mt) {
        #pragma unroll
        for (int r = 0; r < 4; ++r) {
            int row = mt * 16 + lg * 4 + r;
            float mx = sRed[row];
            float sv = 0.f;
            #pragma unroll
            for (int nt = 0; nt < 4; ++nt) sv += __expf(acc[mt][nt][r] - mx);
            #pragma unroll
            for (int msk = 1; msk < 16; msk <<= 1) sv += __shfl_xor(sv, msk);
            if (l15 == 0) sPart[w * 64 + row] = sv;
        }
    }
    __syncthreads();
    if (tid < 64) {
        float mx = sRed[tid];
        float sv = __expf(sTail[tid] - mx);
        #pragma unroll
        for (int ww = 0; ww < 16; ++ww) sv += sPart[ww * 64 + tid];
        sRed[tid] = mx + logf(sv);  // lse
    }
    __syncthreads();   // sRed ready; hlds/wtld dead -> sOut aliasing OK

    // ---- write: 8 groups of 8 rows, staged through LDS, drained as float4 ----
    for (int grp = 0; grp < 8; ++grp) {
        const int mt = grp >> 1;
        const int half8 = grp & 1;
        if ((lg >> 1) == half8) {
            const int row_local = (lg & 1) * 4;
            #pragma unroll
            for (int nt = 0; nt < 4; ++nt) {
                #pragma unroll
                for (int r = 0; r < 4; ++r) {
                    u.sOut[(row_local + r) * 1025 + w * 64 + nt * 16 + l15] =
                        acc[mt][nt][r] - sRed[grp * 8 + row_local + r];
                }
            }
        }
        if (tid < 8) u.sOut[tid * 1025 + 1024] = sTail[grp * 8 + tid] - sRed[grp * 8 + tid];
        __syncthreads();
        // 8*1025 = 8200 floats = 2050 float4, base 16B-aligned
        float* outp = out + (rowbase + grp * 8) * (size_t)V1c;
        #pragma unroll
        for (int k = 0; k < 2; ++k) {
            int i4 = tid + 1024 * k;
            floatx4 v = *(const floatx4*)(&u.sOut[4 * i4]);
            __builtin_nontemporal_store(v, (floatx4*)(outp + 4 * i4));
        }
        if (tid < 2) {
            int i4 = tid + 2048;
            floatx4 v = *(const floatx4*)(&u.sOut[4 * i4]);
            __builtin_nontemporal_store(v, (floatx4*)(outp + 4 * i4));
        }
        __syncthreads();
    }
}

extern "C" void kernel_launch(void* const* d_in, const int* in_sizes, int n_in,
                              void* d_out, int out_size, void* d_ws, size_t ws_size,
                              hipStream_t stream) {
    const float* enc   = (const float*)d_in[0];
    const float* pred  = (const float*)d_in[1];
    const float* Wenc  = (const float*)d_in[2];
    const float* benc  = (const float*)d_in[3];
    const float* Wpred = (const float*)d_in[4];
    const float* bpred = (const float*)d_in[5];
    const float* Wout  = (const float*)d_in[6];
    const float* bout  = (const float*)d_in[7];

    float* f = (float*)d_ws;
    float* g = f + (size_t)Bb * Tt * Dd;
    unsigned short* Wb = (unsigned short*)(g + (size_t)Bb * Uu * Dd);
    float* wtail = (float*)(Wb + 1024 * Dd);

    fg_fused<<<192, 640, 0, stream>>>(enc, Wenc, benc, f, pred, Wpred, bpred, g);
    conv_wout<<<640, 256, 0, stream>>>(Wout, Wb, wtail);
    joint_main<<<Bb * Tt * 2, 1024, 0, stream>>>(f, g, Wb, wtail, bout, (float*)d_out);
}

// Round 9
// 576.383 us; speedup vs baseline: 2.3121x; 1.1192x over previous
//
#include <hip/hip_runtime.h>
#include <hip/hip_bf16.h>

#define Bb 4
#define Tt 256
#define Uu 128
#define H1 512
#define H2 640
#define Dd 640
#define V1c 1025

typedef __bf16 bf16x8 __attribute__((ext_vector_type(8)));
typedef unsigned short ushort8 __attribute__((ext_vector_type(8)));
typedef unsigned short ushort4v __attribute__((ext_vector_type(4)));
typedef float floatx4 __attribute__((ext_vector_type(4)));

static __device__ __forceinline__ unsigned short f2bf(float x) {
    union { float f; unsigned u; } a; a.f = x;
    unsigned r = a.u + 0x7fffu + ((a.u >> 16) & 1u);
    return (unsigned short)(r >> 16);
}
static __device__ __forceinline__ float bf2f(unsigned short x) {
    union { unsigned u; float f; } a; a.u = ((unsigned)x) << 16; return a.f;
}
static __device__ __forceinline__ void gload_lds16(const void* gsrc, void* ldst) {
    __builtin_amdgcn_global_load_lds(
        (const __attribute__((address_space(1))) void*)gsrc,
        (__attribute__((address_space(3))) void*)ldst, 16, 0, 0);
}

// ---------------- f and g linear layers, fused in one launch ----------------
__global__ __launch_bounds__(640) void fg_fused(const float* __restrict__ enc,
                                                const float* __restrict__ Wenc,
                                                const float* __restrict__ benc,
                                                float* __restrict__ f,
                                                const float* __restrict__ pred,
                                                const float* __restrict__ Wpred,
                                                const float* __restrict__ bpred,
                                                float* __restrict__ g) {
    __shared__ float s[640 * 8];
    const bool isF = blockIdx.x < 128;
    const float* in   = isF ? enc : pred;
    const float* W    = isF ? Wenc : Wpred;
    const float* bias = isF ? benc : bpred;
    float* out        = isF ? f : g;
    const int H    = isF ? H1 : H2;
    const int Tdim = isF ? Tt : Uu;
    const int blk  = isF ? (int)blockIdx.x : (int)blockIdx.x - 128;
    const int tBlocks = Tdim >> 3;
    const int b  = blk / tBlocks;
    const int t0 = (blk % tBlocks) << 3;
    const float* inB = in + (size_t)b * H * Tdim + t0;
    const int tid = threadIdx.x;

    for (int h = tid; h < H; h += 640) {
        float4 v0 = *(const float4*)(inB + (size_t)h * Tdim);
        float4 v1 = *(const float4*)(inB + (size_t)h * Tdim + 4);
        *(float4*)(&s[h * 8])     = v0;
        *(float4*)(&s[h * 8 + 4]) = v1;
    }
    __syncthreads();

    const int d = tid;
    float acc[8];
    #pragma unroll
    for (int j = 0; j < 8; ++j) acc[j] = 0.f;
    #pragma unroll 4
    for (int h = 0; h < H; ++h) {
        float w = W[(size_t)h * Dd + d];
        float4 s0 = *(const float4*)(&s[h * 8]);
        float4 s1 = *(const float4*)(&s[h * 8 + 4]);
        acc[0] += s0.x * w; acc[1] += s0.y * w; acc[2] += s0.z * w; acc[3] += s0.w * w;
        acc[4] += s1.x * w; acc[5] += s1.y * w; acc[6] += s1.z * w; acc[7] += s1.w * w;
    }
    float bv = bias[d];
    float* o = out + ((size_t)b * Tdim + t0) * Dd + d;
    #pragma unroll
    for (int j = 0; j < 8; ++j) o[(size_t)j * Dd] = acc[j] + bv;
}

// Wb[v][d] = bf16(W_out[d][v]) for v<1024 ; wtail[d] = W_out[d][1024]
__global__ __launch_bounds__(256) void conv_wout(const float* __restrict__ Wout,
                                                 unsigned short* __restrict__ Wb,
                                                 float* __restrict__ wtail) {
    __shared__ float tile[32][33];
    int tx = threadIdx.x & 31, ty = threadIdx.x >> 5;
    int vb = (blockIdx.x & 31) * 32;
    int db = (blockIdx.x >> 5) * 32;
    #pragma unroll
    for (int j = 0; j < 4; ++j) {
        int dd = db + ty + 8 * j;
        tile[ty + 8 * j][tx] = Wout[(size_t)dd * V1c + vb + tx];
    }
    __syncthreads();
    #pragma unroll
    for (int j = 0; j < 4; ++j) {
        int v = vb + ty + 8 * j;
        Wb[(size_t)v * Dd + db + tx] = f2bf(tile[tx][ty + 8 * j]);
    }
    if (blockIdx.x == 0) {
        for (int dd = threadIdx.x; dd < 640; dd += 256) wtail[dd] = Wout[(size_t)dd * V1c + 1024];
    }
}

// ---------------- h materialization: h[b,t,u,:] = bf16(relu(f+g)) ----------------
// grid 1024 = (b,t); 512 thr; 4 threads per u-row (128 rows), 20 col-octs each.
__global__ __launch_bounds__(512) void h_mat(const float* __restrict__ f,
                                             const float* __restrict__ g,
                                             unsigned short* __restrict__ h) {
    __shared__ float fr[640];
    const int blk = blockIdx.x;
    const int b = blk >> 8;
    const int t = blk & 255;
    const int tid = threadIdx.x;
    if (tid < 160) *(float4*)(&fr[tid * 4]) = *(const float4*)(f + ((size_t)b * Tt + t) * Dd + tid * 4);
    __syncthreads();
    const int u = tid >> 2;      // 0..127
    const int q = tid & 3;
    const float* grow = g + ((size_t)b * Uu + u) * Dd;
    unsigned short* hrow = h + ((size_t)(b * Tt + t) * Uu + u) * (size_t)Dd;
    #pragma unroll 4
    for (int j = 0; j < 20; ++j) {
        int o = j * 4 + q;           // oct 0..79
        int c0 = o * 8;
        float4 ga = *(const float4*)(grow + c0);
        float4 gb = *(const float4*)(grow + c0 + 4);
        float4 fa = *(const float4*)(&fr[c0]);
        float4 fb = *(const float4*)(&fr[c0 + 4]);
        float h0 = fa.x + ga.x; h0 = h0 > 0.f ? h0 : 0.f;
        float h1 = fa.y + ga.y; h1 = h1 > 0.f ? h1 : 0.f;
        float h2 = fa.z + ga.z; h2 = h2 > 0.f ? h2 : 0.f;
        float h3 = fa.w + ga.w; h3 = h3 > 0.f ? h3 : 0.f;
        float h4 = fb.x + gb.x; h4 = h4 > 0.f ? h4 : 0.f;
        float h5 = fb.y + gb.y; h5 = h5 > 0.f ? h5 : 0.f;
        float h6 = fb.z + gb.z; h6 = h6 > 0.f ? h6 : 0.f;
        float h7 = fb.w + gb.w; h7 = h7 > 0.f ? h7 : 0.f;
        ushort8 pk;
        pk[0] = f2bf(h0); pk[1] = f2bf(h1); pk[2] = f2bf(h2); pk[3] = f2bf(h3);
        pk[4] = f2bf(h4); pk[5] = f2bf(h5); pk[6] = f2bf(h6); pk[7] = f2bf(h7);
        *(ushort8*)(hrow + c0) = pk;
    }
}

// ---------------- fused joint + log-softmax, A staged async via global_load_lds ----
// 2048 blocks x 512 thr (8 waves). Block: 64 rows x 1025 cols; wave tile 64x128.
// h-panel halves (64x320 bf16, 656B padded rows) double-buffered; stage(half1)
// issued BEFORE K-loop(half0): global_load_lds has no dest regs, so compiler
// B-load vmcnt waits leave it in flight; __syncthreads() between halves consumes.
// LDS slot trick: slot s -> row s/41, sir s%41 => linear LDS == padded layout.
__global__ __launch_bounds__(512, 2) void joint_main(const unsigned short* __restrict__ h,
                                                     const unsigned short* __restrict__ Wb,
                                                     const float* __restrict__ wtail,
                                                     const float* __restrict__ b_out,
                                                     float* __restrict__ out) {
    __shared__ __align__(16) union UU {
        unsigned short hlds[2 * 64 * 328];   // 2 x 41,984 B
        float sOut[8 * 1025];                // 32,800 B (aliases dead hlds[0] in epilogue)
    } u;
    __shared__ float wtld[640];
    __shared__ float sPart[8 * 64];
    __shared__ float sRed[64];
    __shared__ float sTail[64];

    const int tid = threadIdx.x;
    const int l = tid & 63;
    const int w = tid >> 6;
    const int l15 = l & 15;
    const int lg = l >> 4;

    const int blk = blockIdx.x;
    const int uhalf = blk & 1;
    const int t = (blk >> 1) & 255;
    const int b = blk >> 9;
    const int u0 = uhalf * 64;
    const size_t rowbase = (size_t)(b * Tt + t) * Uu + u0;
    const unsigned short* hbase = h + rowbase * (size_t)Dd;   // 64 contiguous rows

    // stage wtail
    for (int i = tid; i < Dd; i += 512) wtld[i] = wtail[i];

    floatx4 acc[4][8];
    #pragma unroll
    for (int i = 0; i < 4; ++i)
        #pragma unroll
        for (int j = 0; j < 8; ++j) acc[i][j] = (floatx4){0.f, 0.f, 0.f, 0.f};

    const unsigned short* __restrict__ bptr = Wb + (size_t)(w * 128 + l15) * Dd + lg * 8;
    float tailAcc = 0.f;
    const int srow = w * 8 + (l >> 3);
    const int ssub = l & 7;

    // ---- issue stage(half0) ----
    {
        const unsigned short* hsrc = hbase;          // half 0 offset
        #pragma unroll
        for (int r = 0; r < 6; ++r) {
            int s = tid + 512 * r;
            if (s < 2624) {
                unsigned row = (unsigned)s / 41u;
                unsigned sir = (unsigned)s - row * 41u;
                if (sir > 39u) sir = 39u;
                gload_lds16(hsrc + (size_t)row * Dd + sir * 8, &u.hlds[s * 8]);
            }
        }
    }
    __syncthreads();   // stage(h0) + wtld landed

    for (int half = 0; half < 2; ++half) {
        const int dhb = half * 320;
        const int bufo = half * 20992;   // ushort offset of this half's LDS buffer

        if (half == 0) {
            // ---- issue stage(half1) -> hlds[1]; stays in flight under K-loop ----
            const unsigned short* hsrc = hbase + 320;
            #pragma unroll
            for (int r = 0; r < 6; ++r) {
                int s = tid + 512 * r;
                if (s < 2624) {
                    unsigned row = (unsigned)s / 41u;
                    unsigned sir = (unsigned)s - row * 41u;
                    if (sir > 39u) sir = 39u;
                    gload_lds16(hsrc + (size_t)row * Dd + sir * 8, &u.hlds[20992 + s * 8]);
                }
            }
        }

        // ---- K loop: 10 steps of 32, B double-buffered in regs ----
        ushort8 Bbuf[2][8];
        #pragma unroll
        for (int nt = 0; nt < 8; ++nt)
            Bbuf[0][nt] = *(const ushort8*)(bptr + (size_t)nt * 16 * Dd + dhb);
        #pragma unroll
        for (int ks = 0; ks < 10; ++ks) {
            if (ks < 9) {
                #pragma unroll
                for (int nt = 0; nt < 8; ++nt)
                    Bbuf[(ks + 1) & 1][nt] =
                        *(const ushort8*)(bptr + (size_t)nt * 16 * Dd + dhb + (ks + 1) * 32);
            }
            bf16x8 afrag[4];
            #pragma unroll
            for (int mt = 0; mt < 4; ++mt) {
                ushort8 av = *(const ushort8*)(&u.hlds[bufo + (mt * 16 + l15) * 328 + ks * 32 + lg * 8]);
                afrag[mt] = __builtin_bit_cast(bf16x8, av);
            }
            #pragma unroll
            for (int nt = 0; nt < 8; ++nt) {
                bf16x8 bfrag = __builtin_bit_cast(bf16x8, Bbuf[ks & 1][nt]);
                #pragma unroll
                for (int mt = 0; mt < 4; ++mt) {
                    acc[mt][nt] = __builtin_amdgcn_mfma_f32_16x16x32_bf16(
                        afrag[mt], bfrag, acc[mt][nt], 0, 0, 0);
                }
            }
        }

        // ---- tail column partial: dot(h_row, wtail) from LDS ----
        #pragma unroll
        for (int j = 0; j < 10; ++j) {
            int c4 = ssub + 8 * j;
            ushort4v hv = *(const ushort4v*)(&u.hlds[bufo + srow * 328 + c4 * 4]);
            float4 wv = *(const float4*)(&wtld[dhb + c4 * 4]);
            tailAcc += bf2f(hv.x) * wv.x + bf2f(hv.y) * wv.y +
                       bf2f(hv.z) * wv.z + bf2f(hv.w) * wv.w;
        }

        if (half == 0) __syncthreads();   // consume stage(h1); all B loads done
    }

    tailAcc += __shfl_xor(tailAcc, 1);
    tailAcc += __shfl_xor(tailAcc, 2);
    tailAcc += __shfl_xor(tailAcc, 4);
    if (ssub == 0) sTail[srow] = tailAcc + b_out[1024];

    // ---- + b_out ----
    #pragma unroll
    for (int nt = 0; nt < 8; ++nt) {
        float bo = b_out[w * 128 + nt * 16 + l15];
        #pragma unroll
        for (int mt = 0; mt < 4; ++mt)
            #pragma unroll
            for (int r = 0; r < 4; ++r) acc[mt][nt][r] += bo;
    }

    // ---- row max ----
    #pragma unroll
    for (int mt = 0; mt < 4; ++mt) {
        #pragma unroll
        for (int r = 0; r < 4; ++r) {
            float m = acc[mt][0][r];
            #pragma unroll
            for (int nt = 1; nt < 8; ++nt) m = fmaxf(m, acc[mt][nt][r]);
            #pragma unroll
            for (int msk = 1; msk < 16; msk <<= 1) m = fmaxf(m, __shfl_xor(m, msk));
            if (l15 == 0) sPart[w * 64 + mt * 16 + lg * 4 + r] = m;
        }
    }
    __syncthreads();
    if (tid < 64) {
        float m = sTail[tid];
        #pragma unroll
        for (int ww = 0; ww < 8; ++ww) m = fmaxf(m, sPart[ww * 64 + tid]);
        sRed[tid] = m;
    }
    __syncthreads();

    // ---- sum exp ----
    #pragma unroll
    for (int mt = 0; mt < 4; ++mt) {
        #pragma unroll
        for (int r = 0; r < 4; ++r) {
            int row = mt * 16 + lg * 4 + r;
            float mx = sRed[row];
            float sv = 0.f;
            #pragma unroll
            for (int nt = 0; nt < 8; ++nt) sv += __expf(acc[mt][nt][r] - mx);
            #pragma unroll
            for (int msk = 1; msk < 16; msk <<= 1) sv += __shfl_xor(sv, msk);
            if (l15 == 0) sPart[w * 64 + row] = sv;
        }
    }
    __syncthreads();
    if (tid < 64) {
        float mx = sRed[tid];
        float sv = __expf(sTail[tid] - mx);
        #pragma unroll
        for (int ww = 0; ww < 8; ++ww) sv += sPart[ww * 64 + tid];
        sRed[tid] = mx + logf(sv);  // lse
    }
    __syncthreads();   // sRed ready; hlds dead -> sOut aliasing OK

    // ---- write: 8 groups of 8 rows, staged through LDS, drained as float4 ----
    for (int grp = 0; grp < 8; ++grp) {
        const int mt = grp >> 1;
        const int half8 = grp & 1;
        if ((lg >> 1) == half8) {
            const int row_local = (lg & 1) * 4;
            #pragma unroll
            for (int nt = 0; nt < 8; ++nt) {
                #pragma unroll
                for (int r = 0; r < 4; ++r) {
                    u.sOut[(row_local + r) * 1025 + w * 128 + nt * 16 + l15] =
                        acc[mt][nt][r] - sRed[grp * 8 + row_local + r];
                }
            }
        }
        if (tid < 8) u.sOut[tid * 1025 + 1024] = sTail[grp * 8 + tid] - sRed[grp * 8 + tid];
        __syncthreads();
        float* outp = out + (rowbase + grp * 8) * (size_t)V1c;
        #pragma unroll
        for (int k = 0; k < 4; ++k) {
            int i4 = tid + 512 * k;
            floatx4 v = *(const floatx4*)(&u.sOut[4 * i4]);
            __builtin_nontemporal_store(v, (floatx4*)(outp + 4 * i4));
        }
        if (tid < 2) {
            int i4 = tid + 2048;
            floatx4 v = *(const floatx4*)(&u.sOut[4 * i4]);
            __builtin_nontemporal_store(v, (floatx4*)(outp + 4 * i4));
        }
        __syncthreads();
    }
}

// ---------------- fallback (R5 path, in-kernel staging) if ws too small ----------------
__global__ __launch_bounds__(512, 2) void joint_fb(const float* __restrict__ f,
                                                   const float* __restrict__ g,
                                                   const unsigned short* __restrict__ Wb,
                                                   const float* __restrict__ wtail,
                                                   const float* __restrict__ b_out,
                                                   float* __restrict__ out) {
    __shared__ __align__(16) union UU {
        struct { unsigned short hlds[64 * 328]; float wtld[640]; } a;
        float sOut[8 * 1025];
    } u;
    __shared__ float sPart[8 * 64];
    __shared__ float sRed[64];
    __shared__ float sTail[64];

    const int tid = threadIdx.x;
    const int l = tid & 63;
    const int w = tid >> 6;
    const int l15 = l & 15;
    const int lg = l >> 4;

    const int blk = blockIdx.x;
    const int uhalf = blk & 1;
    const int t = (blk >> 1) & 255;
    const int b = blk >> 9;
    const int u0 = uhalf * 64;
    const size_t fbase = ((size_t)b * Tt + t) * Dd;
    const size_t gbase = ((size_t)b * Uu + u0) * Dd;
    const size_t rowbase = (size_t)(b * Tt + t) * Uu + u0;

    for (int i = tid; i < Dd; i += 512) u.a.wtld[i] = wtail[i];

    floatx4 acc[4][8];
    #pragma unroll
    for (int i = 0; i < 4; ++i)
        #pragma unroll
        for (int j = 0; j < 8; ++j) acc[i][j] = (floatx4){0.f, 0.f, 0.f, 0.f};

    const unsigned short* __restrict__ bptr = Wb + (size_t)(w * 128 + l15) * Dd + lg * 8;
    float tailAcc = 0.f;
    const int srow = w * 8 + (l >> 3);
    const int ssub = l & 7;

    for (int half = 0; half < 2; ++half) {
        const int dhb = half * 320;
        __syncthreads();
        {
            const int row = tid >> 3;
            #pragma unroll
            for (int j = 0; j < 10; ++j) {
                int c4 = (tid & 7) + 8 * j;
                int d = dhb + c4 * 4;
                float4 fv = *(const float4*)(f + fbase + d);
                float4 gv = *(const float4*)(g + gbase + (size_t)row * Dd + d);
                float h0 = fv.x + gv.x; h0 = h0 > 0.f ? h0 : 0.f;
                float h1 = fv.y + gv.y; h1 = h1 > 0.f ? h1 : 0.f;
                float h2 = fv.z + gv.z; h2 = h2 > 0.f ? h2 : 0.f;
                float h3 = fv.w + gv.w; h3 = h3 > 0.f ? h3 : 0.f;
                ushort4v pk;
                pk.x = f2bf(h0); pk.y = f2bf(h1); pk.z = f2bf(h2); pk.w = f2bf(h3);
                *(ushort4v*)(&u.a.hlds[row * 328 + c4 * 4]) = pk;
            }
        }
        __syncthreads();

        ushort8 Bbuf[2][8];
        #pragma unroll
        for (int nt = 0; nt < 8; ++nt)
            Bbuf[0][nt] = *(const ushort8*)(bptr + (size_t)nt * 16 * Dd + dhb);
        #pragma unroll
        for (int ks = 0; ks < 10; ++ks) {
            if (ks < 9) {
                #pragma unroll
                for (int nt = 0; nt < 8; ++nt)
                    Bbuf[(ks + 1) & 1][nt] =
                        *(const ushort8*)(bptr + (size_t)nt * 16 * Dd + dhb + (ks + 1) * 32);
            }
            bf16x8 afrag[4];
            #pragma unroll
            for (int mt = 0; mt < 4; ++mt) {
                ushort8 av = *(const ushort8*)(&u.a.hlds[(mt * 16 + l15) * 328 + ks * 32 + lg * 8]);
                afrag[mt] = __builtin_bit_cast(bf16x8, av);
            }
            #pragma unroll
            for (int nt = 0; nt < 8; ++nt) {
                bf16x8 bfrag = __builtin_bit_cast(bf16x8, Bbuf[ks & 1][nt]);
                #pragma unroll
                for (int mt = 0; mt < 4; ++mt) {
                    acc[mt][nt] = __builtin_amdgcn_mfma_f32_16x16x32_bf16(
                        afrag[mt], bfrag, acc[mt][nt], 0, 0, 0);
                }
            }
        }
        #pragma unroll
        for (int j = 0; j < 10; ++j) {
            int c4 = ssub + 8 * j;
            ushort4v hv = *(const ushort4v*)(&u.a.hlds[srow * 328 + c4 * 4]);
            float4 wv = *(const float4*)(&u.a.wtld[dhb + c4 * 4]);
            tailAcc += bf2f(hv.x) * wv.x + bf2f(hv.y) * wv.y +
                       bf2f(hv.z) * wv.z + bf2f(hv.w) * wv.w;
        }
    }

    tailAcc += __shfl_xor(tailAcc, 1);
    tailAcc += __shfl_xor(tailAcc, 2);
    tailAcc += __shfl_xor(tailAcc, 4);
    if (ssub == 0) sTail[srow] = tailAcc + b_out[1024];

    #pragma unroll
    for (int nt = 0; nt < 8; ++nt) {
        float bo = b_out[w * 128 + nt * 16 + l15];
        #pragma unroll
        for (int mt = 0; mt < 4; ++mt)
            #pragma unroll
            for (int r = 0; r < 4; ++r) acc[mt][nt][r] += bo;
    }

    #pragma unroll
    for (int mt = 0; mt < 4; ++mt) {
        #pragma unroll
        for (int r = 0; r < 4; ++r) {
            float m = acc[mt][0][r];
            #pragma unroll
            for (int nt = 1; nt < 8; ++nt) m = fmaxf(m, acc[mt][nt][r]);
            #pragma unroll
            for (int msk = 1; msk < 16; msk <<= 1) m = fmaxf(m, __shfl_xor(m, msk));
            if (l15 == 0) sPart[w * 64 + mt * 16 + lg * 4 + r] = m;
        }
    }
    __syncthreads();
    if (tid < 64) {
        float m = sTail[tid];
        #pragma unroll
        for (int ww = 0; ww < 8; ++ww) m = fmaxf(m, sPart[ww * 64 + tid]);
        sRed[tid] = m;
    }
    __syncthreads();

    #pragma unroll
    for (int mt = 0; mt < 4; ++mt) {
        #pragma unroll
        for (int r = 0; r < 4; ++r) {
            int row = mt * 16 + lg * 4 + r;
            float mx = sRed[row];
            float sv = 0.f;
            #pragma unroll
            for (int nt = 0; nt < 8; ++nt) sv += __expf(acc[mt][nt][r] - mx);
            #pragma unroll
            for (int msk = 1; msk < 16; msk <<= 1) sv += __shfl_xor(sv, msk);
            if (l15 == 0) sPart[w * 64 + row] = sv;
        }
    }
    __syncthreads();
    if (tid < 64) {
        float mx = sRed[tid];
        float sv = __expf(sTail[tid] - mx);
        #pragma unroll
        for (int ww = 0; ww < 8; ++ww) sv += sPart[ww * 64 + tid];
        sRed[tid] = mx + logf(sv);
    }
    __syncthreads();

    for (int grp = 0; grp < 8; ++grp) {
        const int mt = grp >> 1;
        const int half8 = grp & 1;
        if ((lg >> 1) == half8) {
            const int row_local = (lg & 1) * 4;
            #pragma unroll
            for (int nt = 0; nt < 8; ++nt) {
                #pragma unroll
                for (int r = 0; r < 4; ++r) {
                    u.sOut[(row_local + r) * 1025 + w * 128 + nt * 16 + l15] =
                        acc[mt][nt][r] - sRed[grp * 8 + row_local + r];
                }
            }
        }
        if (tid < 8) u.sOut[tid * 1025 + 1024] = sTail[grp * 8 + tid] - sRed[grp * 8 + tid];
        __syncthreads();
        float* outp = out + (rowbase + grp * 8) * (size_t)V1c;
        #pragma unroll
        for (int k = 0; k < 4; ++k) {
            int i4 = tid + 512 * k;
            floatx4 v = *(const floatx4*)(&u.sOut[4 * i4]);
            __builtin_nontemporal_store(v, (floatx4*)(outp + 4 * i4));
        }
        if (tid < 2) {
            int i4 = tid + 2048;
            floatx4 v = *(const floatx4*)(&u.sOut[4 * i4]);
            __builtin_nontemporal_store(v, (floatx4*)(outp + 4 * i4));
        }
        __syncthreads();
    }
}

extern "C" void kernel_launch(void* const* d_in, const int* in_sizes, int n_in,
                              void* d_out, int out_size, void* d_ws, size_t ws_size,
                              hipStream_t stream) {
    const float* enc   = (const float*)d_in[0];
    const float* pred  = (const float*)d_in[1];
    const float* Wenc  = (const float*)d_in[2];
    const float* benc  = (const float*)d_in[3];
    const float* Wpred = (const float*)d_in[4];
    const float* bpred = (const float*)d_in[5];
    const float* Wout  = (const float*)d_in[6];
    const float* bout  = (const float*)d_in[7];

    float* f = (float*)d_ws;                                   // 2.62 MB
    float* g = f + (size_t)Bb * Tt * Dd;                       // 1.31 MB
    unsigned short* Wb = (unsigned short*)(g + (size_t)Bb * Uu * Dd);  // 1.31 MB
    float* wtail = (float*)(Wb + 1024 * Dd);                   // 2.5 KB
    unsigned short* h = (unsigned short*)((char*)d_ws + 6ull * 1024 * 1024);  // 168 MB
    const size_t need = 6ull * 1024 * 1024 + (size_t)Bb * Tt * Uu * Dd * 2;

    fg_fused<<<192, 640, 0, stream>>>(enc, Wenc, benc, f, pred, Wpred, bpred, g);
    conv_wout<<<640, 256, 0, stream>>>(Wout, Wb, wtail);
    if (ws_size >= need) {
        h_mat<<<Bb * Tt, 512, 0, stream>>>(f, g, h);
        joint_main<<<Bb * Tt * 2, 512, 0, stream>>>(h, Wb, wtail, bout, (float*)d_out);
    } else {
        joint_fb<<<Bb * Tt * 2, 512, 0, stream>>>(f, g, Wb, wtail, bout, (float*)d_out);
    }
}

// Round 10
// 446.776 us; speedup vs baseline: 2.9828x; 1.2901x over previous
//
#include <hip/hip_runtime.h>
#include <hip/hip_bf16.h>

#define Bb 4
#define Tt 256
#define Uu 128
#define H1 512
#define H2 640
#define Dd 640
#define V1c 1025

typedef __bf16 bf16x8 __attribute__((ext_vector_type(8)));
typedef unsigned short ushort8 __attribute__((ext_vector_type(8)));
typedef unsigned short ushort4v __attribute__((ext_vector_type(4)));
typedef float floatx4 __attribute__((ext_vector_type(4)));

static __device__ __forceinline__ unsigned short f2bf(float x) {
    union { float f; unsigned u; } a; a.f = x;
    unsigned r = a.u + 0x7fffu + ((a.u >> 16) & 1u);
    return (unsigned short)(r >> 16);
}
static __device__ __forceinline__ float bf2f(unsigned short x) {
    union { unsigned u; float f; } a; a.u = ((unsigned)x) << 16; return a.f;
}

// ---------------- f and g linear layers, fused in one launch ----------------
__global__ __launch_bounds__(640) void fg_fused(const float* __restrict__ enc,
                                                const float* __restrict__ Wenc,
                                                const float* __restrict__ benc,
                                                float* __restrict__ f,
                                                const float* __restrict__ pred,
                                                const float* __restrict__ Wpred,
                                                const float* __restrict__ bpred,
                                                float* __restrict__ g) {
    __shared__ float s[640 * 8];
    const bool isF = blockIdx.x < 128;
    const float* in   = isF ? enc : pred;
    const float* W    = isF ? Wenc : Wpred;
    const float* bias = isF ? benc : bpred;
    float* out        = isF ? f : g;
    const int H    = isF ? H1 : H2;
    const int Tdim = isF ? Tt : Uu;
    const int blk  = isF ? (int)blockIdx.x : (int)blockIdx.x - 128;
    const int tBlocks = Tdim >> 3;
    const int b  = blk / tBlocks;
    const int t0 = (blk % tBlocks) << 3;
    const float* inB = in + (size_t)b * H * Tdim + t0;
    const int tid = threadIdx.x;

    for (int h = tid; h < H; h += 640) {
        float4 v0 = *(const float4*)(inB + (size_t)h * Tdim);
        float4 v1 = *(const float4*)(inB + (size_t)h * Tdim + 4);
        *(float4*)(&s[h * 8])     = v0;
        *(float4*)(&s[h * 8 + 4]) = v1;
    }
    __syncthreads();

    const int d = tid;
    float acc[8];
    #pragma unroll
    for (int j = 0; j < 8; ++j) acc[j] = 0.f;
    #pragma unroll 4
    for (int h = 0; h < H; ++h) {
        float w = W[(size_t)h * Dd + d];
        float4 s0 = *(const float4*)(&s[h * 8]);
        float4 s1 = *(const float4*)(&s[h * 8 + 4]);
        acc[0] += s0.x * w; acc[1] += s0.y * w; acc[2] += s0.z * w; acc[3] += s0.w * w;
        acc[4] += s1.x * w; acc[5] += s1.y * w; acc[6] += s1.z * w; acc[7] += s1.w * w;
    }
    float bv = bias[d];
    float* o = out + ((size_t)b * Tdim + t0) * Dd + d;
    #pragma unroll
    for (int j = 0; j < 8; ++j) o[(size_t)j * Dd] = acc[j] + bv;
}

// ---------------- W_out -> Wb2 swizzled fragment layout + wtail ----------------
// Wb2[w][ksg][nt][l15][lg][8] (ushort): the exact per-(wave,k-step) B-fragment
// order of the joint kernel, so every B-load instruction reads 1KB CONTIGUOUS
// (16 sequential 64B lines) instead of 16 scattered segments.
// ushort offset = w*81920 + ksg*4096 + nt*512 + l15*32 + lg*8 + j
// source: v = w*128 + nt*16 + l15 ; d = ksg*32 + lg*8 + j
// grid: 160 blocks = (w 0..7) x (ksg 0..19), 256 thr.
__global__ __launch_bounds__(256) void conv_wout2(const float* __restrict__ Wout,
                                                  unsigned short* __restrict__ Wb2,
                                                  float* __restrict__ wtail) {
    __shared__ float tile[32][128];
    const int blk = blockIdx.x;
    const int w = blk / 20;
    const int db = blk % 20;          // = ksg ; d range db*32..+32
    const int tid = threadIdx.x;

    #pragma unroll
    for (int i = 0; i < 16; ++i) {
        int idx = tid + 256 * i;      // 0..4095
        int d_loc = idx >> 7;         // 0..31
        int v_loc = idx & 127;        // 0..127
        tile[d_loc][v_loc] = Wout[(size_t)(db * 32 + d_loc) * V1c + w * 128 + v_loc];
    }
    __syncthreads();

    #pragma unroll
    for (int k = 0; k < 2; ++k) {
        int gidx = tid * 2 + k;       // 0..511
        int nt  = gidx >> 6;
        int rem = gidx & 63;
        int l15 = rem >> 2;
        int lg  = rem & 3;
        int v_loc = nt * 16 + l15;
        ushort8 pk;
        #pragma unroll
        for (int j = 0; j < 8; ++j) pk[j] = f2bf(tile[lg * 8 + j][v_loc]);
        *(ushort8*)(Wb2 + (size_t)w * 81920 + db * 4096 + gidx * 8) = pk;
    }

    if (blk == 0) {
        for (int dd = tid; dd < Dd; dd += 256) wtail[dd] = Wout[(size_t)dd * V1c + 1024];
    }
}

// ---------------- fused joint + log-softmax ----------------
// 2048 blocks x 512 thr (8 waves). Block: 64 rows x 1025 cols; wave tile 64x128.
// R5 structure; ONLY change: B loads read the contiguous Wb2 fragment layout.
__global__ __launch_bounds__(512, 2) void joint_main(const float* __restrict__ f,
                                                     const float* __restrict__ g,
                                                     const unsigned short* __restrict__ Wb2,
                                                     const float* __restrict__ wtail,
                                                     const float* __restrict__ b_out,
                                                     float* __restrict__ out) {
    __shared__ __align__(16) union UU {
        struct { unsigned short hlds[64 * 328]; float wtld[640]; } a;  // 44544 B
        float sOut[8 * 1025];                                          // 32800 B
    } u;
    __shared__ float sPart[8 * 64];
    __shared__ float sRed[64];
    __shared__ float sTail[64];

    const int tid = threadIdx.x;
    const int l = tid & 63;
    const int w = tid >> 6;
    const int l15 = l & 15;
    const int lg = l >> 4;

    const int blk = blockIdx.x;
    const int uhalf = blk & 1;
    const int t = (blk >> 1) & 255;
    const int b = blk >> 9;
    const int u0 = uhalf * 64;
    const size_t fbase = ((size_t)b * Tt + t) * Dd;
    const size_t gbase = ((size_t)b * Uu + u0) * Dd;
    const size_t rowbase = (size_t)(b * Tt + t) * Uu + u0;

    // stage wtail (fp32) into LDS
    for (int i = tid; i < Dd; i += 512) u.a.wtld[i] = wtail[i];

    floatx4 acc[4][8];
    #pragma unroll
    for (int i = 0; i < 4; ++i)
        #pragma unroll
        for (int j = 0; j < 8; ++j) acc[i][j] = (floatx4){0.f, 0.f, 0.f, 0.f};

    // per-lane base into the swizzled fragment layout
    const unsigned short* __restrict__ bbase = Wb2 + (size_t)w * 81920 + (l15 * 32 + lg * 8);
    float tailAcc = 0.f;
    const int srow = w * 8 + (l >> 3);
    const int ssub = l & 7;

    for (int half = 0; half < 2; ++half) {
        const int dhb = half * 320;
        __syncthreads();
        // ---- stage h = relu(f+g) panel: 64 rows x 320 cols bf16 ----
        {
            const int row = tid >> 3;
            #pragma unroll
            for (int j = 0; j < 10; ++j) {
                int c4 = (tid & 7) + 8 * j;
                int d = dhb + c4 * 4;
                float4 fv = *(const float4*)(f + fbase + d);
                float4 gv = *(const float4*)(g + gbase + (size_t)row * Dd + d);
                float h0 = fv.x + gv.x; h0 = h0 > 0.f ? h0 : 0.f;
                float h1 = fv.y + gv.y; h1 = h1 > 0.f ? h1 : 0.f;
                float h2 = fv.z + gv.z; h2 = h2 > 0.f ? h2 : 0.f;
                float h3 = fv.w + gv.w; h3 = h3 > 0.f ? h3 : 0.f;
                ushort4v pk;
                pk.x = f2bf(h0); pk.y = f2bf(h1); pk.z = f2bf(h2); pk.w = f2bf(h3);
                *(ushort4v*)(&u.a.hlds[row * 328 + c4 * 4]) = pk;
            }
        }
        __syncthreads();

        // ---- K loop: 10 steps of 32, B double-buffered in regs ----
        ushort8 Bbuf[2][8];
        {
            const int ksg0 = half * 10;
            #pragma unroll
            for (int nt = 0; nt < 8; ++nt)
                Bbuf[0][nt] = *(const ushort8*)(bbase + ksg0 * 4096 + nt * 512);
        }
        #pragma unroll
        for (int ks = 0; ks < 10; ++ks) {
            const int ksg = half * 10 + ks;
            if (ks < 9) {
                #pragma unroll
                for (int nt = 0; nt < 8; ++nt)
                    Bbuf[(ks + 1) & 1][nt] =
                        *(const ushort8*)(bbase + (ksg + 1) * 4096 + nt * 512);
            }
            bf16x8 afrag[4];
            #pragma unroll
            for (int mt = 0; mt < 4; ++mt) {
                ushort8 av = *(const ushort8*)(&u.a.hlds[(mt * 16 + l15) * 328 + ks * 32 + lg * 8]);
                afrag[mt] = __builtin_bit_cast(bf16x8, av);
            }
            #pragma unroll
            for (int nt = 0; nt < 8; ++nt) {
                bf16x8 bfrag = __builtin_bit_cast(bf16x8, Bbuf[ks & 1][nt]);
                #pragma unroll
                for (int mt = 0; mt < 4; ++mt) {
                    acc[mt][nt] = __builtin_amdgcn_mfma_f32_16x16x32_bf16(
                        afrag[mt], bfrag, acc[mt][nt], 0, 0, 0);
                }
            }
        }

        // ---- tail column partial: dot(h_row, wtail) from LDS ----
        #pragma unroll
        for (int j = 0; j < 10; ++j) {
            int c4 = ssub + 8 * j;
            ushort4v hv = *(const ushort4v*)(&u.a.hlds[srow * 328 + c4 * 4]);
            float4 wv = *(const float4*)(&u.a.wtld[dhb + c4 * 4]);
            tailAcc += bf2f(hv.x) * wv.x + bf2f(hv.y) * wv.y +
                       bf2f(hv.z) * wv.z + bf2f(hv.w) * wv.w;
        }
    }

    tailAcc += __shfl_xor(tailAcc, 1);
    tailAcc += __shfl_xor(tailAcc, 2);
    tailAcc += __shfl_xor(tailAcc, 4);
    if (ssub == 0) sTail[srow] = tailAcc + b_out[1024];

    // ---- + b_out ----
    #pragma unroll
    for (int nt = 0; nt < 8; ++nt) {
        float bo = b_out[w * 128 + nt * 16 + l15];
        #pragma unroll
        for (int mt = 0; mt < 4; ++mt)
            #pragma unroll
            for (int r = 0; r < 4; ++r) acc[mt][nt][r] += bo;
    }

    // ---- row max ----
    #pragma unroll
    for (int mt = 0; mt < 4; ++mt) {
        #pragma unroll
        for (int r = 0; r < 4; ++r) {
            float m = acc[mt][0][r];
            #pragma unroll
            for (int nt = 1; nt < 8; ++nt) m = fmaxf(m, acc[mt][nt][r]);
            #pragma unroll
            for (int msk = 1; msk < 16; msk <<= 1) m = fmaxf(m, __shfl_xor(m, msk));
            if (l15 == 0) sPart[w * 64 + mt * 16 + lg * 4 + r] = m;
        }
    }
    __syncthreads();
    if (tid < 64) {
        float m = sTail[tid];
        #pragma unroll
        for (int ww = 0; ww < 8; ++ww) m = fmaxf(m, sPart[ww * 64 + tid]);
        sRed[tid] = m;
    }
    __syncthreads();

    // ---- sum exp ----
    #pragma unroll
    for (int mt = 0; mt < 4; ++mt) {
        #pragma unroll
        for (int r = 0; r < 4; ++r) {
            int row = mt * 16 + lg * 4 + r;
            float mx = sRed[row];
            float sv = 0.f;
            #pragma unroll
            for (int nt = 0; nt < 8; ++nt) sv += __expf(acc[mt][nt][r] - mx);
            #pragma unroll
            for (int msk = 1; msk < 16; msk <<= 1) sv += __shfl_xor(sv, msk);
            if (l15 == 0) sPart[w * 64 + row] = sv;
        }
    }
    __syncthreads();
    if (tid < 64) {
        float mx = sRed[tid];
        float sv = __expf(sTail[tid] - mx);
        #pragma unroll
        for (int ww = 0; ww < 8; ++ww) sv += sPart[ww * 64 + tid];
        sRed[tid] = mx + logf(sv);  // lse
    }
    __syncthreads();   // sRed ready; hlds/wtld dead -> sOut aliasing OK

    // ---- write: 8 groups of 8 rows, staged through LDS, drained as float4 ----
    for (int grp = 0; grp < 8; ++grp) {
        const int mt = grp >> 1;
        const int half8 = grp & 1;
        if ((lg >> 1) == half8) {
            const int row_local = (lg & 1) * 4;
            #pragma unroll
            for (int nt = 0; nt < 8; ++nt) {
                #pragma unroll
                for (int r = 0; r < 4; ++r) {
                    u.sOut[(row_local + r) * 1025 + w * 128 + nt * 16 + l15] =
                        acc[mt][nt][r] - sRed[grp * 8 + row_local + r];
                }
            }
        }
        if (tid < 8) u.sOut[tid * 1025 + 1024] = sTail[grp * 8 + tid] - sRed[grp * 8 + tid];
        __syncthreads();
        // 8*1025 = 8200 floats = 2050 float4, base 16B-aligned
        float* outp = out + (rowbase + grp * 8) * (size_t)V1c;
        #pragma unroll
        for (int k = 0; k < 4; ++k) {
            int i4 = tid + 512 * k;
            floatx4 v = *(const floatx4*)(&u.sOut[4 * i4]);
            __builtin_nontemporal_store(v, (floatx4*)(outp + 4 * i4));
        }
        if (tid < 2) {
            int i4 = tid + 2048;
            floatx4 v = *(const floatx4*)(&u.sOut[4 * i4]);
            __builtin_nontemporal_store(v, (floatx4*)(outp + 4 * i4));
        }
        __syncthreads();
    }
}

extern "C" void kernel_launch(void* const* d_in, const int* in_sizes, int n_in,
                              void* d_out, int out_size, void* d_ws, size_t ws_size,
                              hipStream_t stream) {
    const float* enc   = (const float*)d_in[0];
    const float* pred  = (const float*)d_in[1];
    const float* Wenc  = (const float*)d_in[2];
    const float* benc  = (const float*)d_in[3];
    const float* Wpred = (const float*)d_in[4];
    const float* bpred = (const float*)d_in[5];
    const float* Wout  = (const float*)d_in[6];
    const float* bout  = (const float*)d_in[7];

    float* f = (float*)d_ws;                                     // 655360 f32
    float* g = f + (size_t)Bb * Tt * Dd;                         // 327680 f32
    unsigned short* Wb2 = (unsigned short*)(g + (size_t)Bb * Uu * Dd);  // 655360 u16
    float* wtail = (float*)(Wb2 + 8 * 81920);                    // 640 f32

    fg_fused<<<192, 640, 0, stream>>>(enc, Wenc, benc, f, pred, Wpred, bpred, g);
    conv_wout2<<<160, 256, 0, stream>>>(Wout, Wb2, wtail);
    joint_main<<<Bb * Tt * 2, 512, 0, stream>>>(f, g, Wb2, wtail, bout, (float*)d_out);
}